// Round 11
// baseline (2593.848 us; speedup 1.0000x reference)
//
#include <hip/hip_runtime.h>
#include <hip/hip_bf16.h>

#define MROWS 16384   // B*L
#define DDIM  512
#define HDIM  1024
#define CDIM  8192
#define LN_EPS 1e-5f
#define CAND_MAX 64
#define SCORE_DELTA 40.0f

typedef __attribute__((ext_vector_type(8))) short bf16x8;
typedef __attribute__((ext_vector_type(4))) float f32x4;
typedef __attribute__((ext_vector_type(16))) float f32x16;
typedef __attribute__((ext_vector_type(4))) int i32x4;
typedef __attribute__((ext_vector_type(8))) int i32x8;

__device__ __forceinline__ unsigned int f2key(float f) {
  unsigned int b = __float_as_uint(f);
  return (b & 0x80000000u) ? ~b : (b | 0x80000000u);
}
__device__ __forceinline__ float key2f(unsigned int k) {
  unsigned int b = (k & 0x80000000u) ? (k ^ 0x80000000u) : ~k;
  return __uint_as_float(b);
}

// Deterministic fp32 -> OCP e4m3fn (RNE, saturate to +-448). Software path:
// no intrinsic-API risk, and A/B sides use the identical mapping.
__device__ __forceinline__ unsigned char f32_to_e4m3(float f) {
  unsigned u = __float_as_uint(f);
  unsigned char sgn = (unsigned char)((u >> 24) & 0x80);
  unsigned ax = u & 0x7FFFFFFFu;
  float af = __uint_as_float(ax);
  if (af >= 448.f) return sgn | 0x7E;
  if (af < 0.015625f) {                 // subnormal: step 2^-9
    int m = (int)rintf(af * 512.f);
    if (m >= 8) return sgn | 0x08;
    return sgn | (unsigned char)m;
  }
  unsigned r = ax + 0x7FFFFu + ((ax >> 20) & 1u);   // RNE at mantissa bit 20
  int e = (int)(r >> 23) - 127 + 7;
  unsigned mant = (r >> 20) & 7u;
  if (e > 15 || (e == 15 && mant == 7)) return sgn | 0x7E;
  return sgn | (unsigned char)((e << 3) | mant);
}

// hi/lo bf16 split: x ~= hi + lo, captures ~17 mantissa bits.
__device__ __forceinline__ void bsplit(float v, unsigned short& h, unsigned short& l) {
  union { __hip_bfloat16 b; unsigned short u; } cv;
  cv.b = __float2bfloat16(v);
  h = cv.u;
  float fh = __bfloat162float(cv.b);
  cv.b = __float2bfloat16(v - fh);
  l = cv.u;
}

// -------- LayerNorm -> fp8 e4m3 (one wave per row, 4 rows/block) + init ------
__global__ __launch_bounds__(256) void k_lnq(const float* __restrict__ x,
                                             const float* __restrict__ lnw,
                                             const float* __restrict__ lnb,
                                             unsigned char* __restrict__ xq,
                                             unsigned int* __restrict__ cnt,
                                             unsigned int* __restrict__ rmin) {
  const int row = blockIdx.x * 4 + (threadIdx.x >> 6);
  const int t = threadIdx.x & 63;
  if (threadIdx.x < 4) {
    const int g = blockIdx.x * 4 + threadIdx.x;
    cnt[g] = 0u;
    rmin[g] = 0xFFFFFFFFu;
  }
  const float4* xr = (const float4*)(x + (size_t)row * DDIM);
  float4 v0 = xr[2 * t + 0];
  float4 v1 = xr[2 * t + 1];
  float s = v0.x + v0.y + v0.z + v0.w + v1.x + v1.y + v1.z + v1.w;
#pragma unroll
  for (int m = 1; m < 64; m <<= 1) s += __shfl_xor(s, m, 64);
  const float mu = s * (1.0f / DDIM);
  float a0 = v0.x - mu, a1 = v0.y - mu, a2 = v0.z - mu, a3 = v0.w - mu;
  float a4 = v1.x - mu, a5 = v1.y - mu, a6 = v1.z - mu, a7 = v1.w - mu;
  float q = a0*a0 + a1*a1 + a2*a2 + a3*a3 + a4*a4 + a5*a5 + a6*a6 + a7*a7;
#pragma unroll
  for (int m = 1; m < 64; m <<= 1) q += __shfl_xor(q, m, 64);
  const float inv = rsqrtf(q * (1.0f / DDIM) + LN_EPS);
  const float4* wr = (const float4*)lnw;
  const float4* br = (const float4*)lnb;
  float4 w0 = wr[2*t+0], w1 = wr[2*t+1];
  float4 b0 = br[2*t+0], b1 = br[2*t+1];
  float y[8];
  y[0] = a0*inv*w0.x + b0.x;  y[1] = a1*inv*w0.y + b0.y;
  y[2] = a2*inv*w0.z + b0.z;  y[3] = a3*inv*w0.w + b0.w;
  y[4] = a4*inv*w1.x + b1.x;  y[5] = a5*inv*w1.y + b1.y;
  y[6] = a6*inv*w1.z + b1.z;  y[7] = a7*inv*w1.w + b1.w;
  unsigned int w0b = 0, w1b = 0;
#pragma unroll
  for (int j = 0; j < 4; ++j) w0b |= (unsigned int)f32_to_e4m3(y[j]) << (8*j);
#pragma unroll
  for (int j = 0; j < 4; ++j) w1b |= (unsigned int)f32_to_e4m3(y[4+j]) << (8*j);
  *(uint2*)(xq + (size_t)row * DDIM + 8 * t) = make_uint2(w0b, w1b);
}

// ---- W[1024][512] -> WTh/WTl [512][1024] bf16 (transpose + hi/lo split) -----
__global__ __launch_bounds__(256) void k_wsplit(const float* __restrict__ W,
                                                unsigned short* __restrict__ WTh,
                                                unsigned short* __restrict__ WTl) {
  const int c = blockIdx.x * 64 + (threadIdx.x & 63);
  const int seg = threadIdx.x >> 6;
  for (int h0 = seg * 256; h0 < seg * 256 + 256; h0 += 8) {
    union { unsigned short u[8]; uint4 v; } oh, ol;
#pragma unroll
    for (int j = 0; j < 8; ++j) {
      float v = W[(size_t)(h0 + j) * DDIM + c];
      bsplit(v, oh.u[j], ol.u[j]);
    }
    *(uint4*)(WTh + (size_t)c * HDIM + h0) = oh.v;
    *(uint4*)(WTl + (size_t)c * HDIM + h0) = ol.v;
  }
}

// ---- cb[1024][8192] -> cbTh/cbTl [8192][1024] bf16 + csq (fp64, determ.) ----
__global__ __launch_bounds__(256) void k_cbsplit(const float* __restrict__ cb,
                                                 unsigned short* __restrict__ cbTh,
                                                 unsigned short* __restrict__ cbTl,
                                                 float* __restrict__ csq_f,
                                                 double* __restrict__ csq_d) {
  __shared__ double part[4][64];
  const int cl = threadIdx.x & 63;
  const int c = blockIdx.x * 64 + cl;
  const int seg = threadIdx.x >> 6;
  double sq = 0.0;
  for (int h0 = seg * 256; h0 < seg * 256 + 256; h0 += 8) {
    union { unsigned short u[8]; uint4 v; } oh, ol;
#pragma unroll
    for (int j = 0; j < 8; ++j) {
      float v = cb[(size_t)(h0 + j) * CDIM + c];
      sq += (double)v * (double)v;
      bsplit(v, oh.u[j], ol.u[j]);
    }
    *(uint4*)(cbTh + (size_t)c * HDIM + h0) = oh.v;
    *(uint4*)(cbTl + (size_t)c * HDIM + h0) = ol.v;
  }
  part[seg][cl] = sq;
  __syncthreads();
  if (threadIdx.x < 64) {
    double a = ((part[0][threadIdx.x] + part[1][threadIdx.x]) +
                part[2][threadIdx.x]) + part[3][threadIdx.x];
    csq_d[c] = a;
    csq_f[c] = (float)a;
  }
}

#define GLL(SRC, DST) __builtin_amdgcn_global_load_lds( \
    (const __attribute__((address_space(1))) unsigned int*)(SRC), \
    (__attribute__((address_space(3))) unsigned int*)(DST), 16, 0, 0)

// ==== Gt[n][d] via bf16x3 MFMA: 64n x 128d tile, K=1024, BK=32, dbuf =========
// (verified R10 engine, unchanged except epilogue: Gt fp32 + Gtq fp8)
#define GSTAGE(KT) { \
  const int rb_ = ((KT) & 1) * 24576; \
  const int co_ = (KT)*32 + sce*8; \
  GLL(gAh + (size_t)sr0 * HDIM + co_,        lds + rb_ +          t*16); \
  GLL(gAl + (size_t)sr0 * HDIM + co_,        lds + rb_ +  4096 +  t*16); \
  GLL(gBh + (size_t)sr0 * HDIM + co_,        lds + rb_ +  8192 +  t*16); \
  GLL(gBh + (size_t)(sr0 + 64) * HDIM + co_, lds + rb_ + 12288 +  t*16); \
  GLL(gBl + (size_t)sr0 * HDIM + co_,        lds + rb_ + 16384 +  t*16); \
  GLL(gBl + (size_t)(sr0 + 64) * HDIM + co_, lds + rb_ + 20480 +  t*16); }

__global__ __launch_bounds__(256) void k_gproj2(
    const unsigned short* __restrict__ cbTh, const unsigned short* __restrict__ cbTl,
    const unsigned short* __restrict__ WTh,  const unsigned short* __restrict__ WTl,
    float* __restrict__ Gt, unsigned char* __restrict__ Gtq) {
  __shared__ __align__(16) char lds[49152];
  const int t = threadIdx.x;
  const int wave = t >> 6;
  const int lane = t & 63;
  const int l15 = lane & 15;
  const int l4  = lane >> 4;
  const int wm = wave >> 1;
  const int wn = wave & 1;

  const int bid = blockIdx.x;
  const int sbid = (bid & 7) * 64 + (bid >> 3);
  const int d_blk = sbid >> 7;
  const int m_blk = sbid & 127;
  const int rowbase = m_blk * 64;
  const int colbase = d_blk * 128;

  const unsigned short* gAh = cbTh + (size_t)rowbase * HDIM;
  const unsigned short* gAl = cbTl + (size_t)rowbase * HDIM;
  const unsigned short* gBh = WTh + (size_t)colbase * HDIM;
  const unsigned short* gBl = WTl + (size_t)colbase * HDIM;

  const int sr0 = t >> 2;
  const int sce = (t & 3) ^ ((t >> 3) & 3);

  const int swz = ((l4 ^ ((l15 >> 1) & 3)) << 4);
  const int aoffb = (wm * 32 + l15) * 64 + swz;
  const int boffb = (wn * 64 + l15) * 64 + swz;

  f32x4 acc[2][4];
#pragma unroll
  for (int i = 0; i < 2; ++i)
#pragma unroll
    for (int j = 0; j < 4; ++j) acc[i][j] = (f32x4){0.f, 0.f, 0.f, 0.f};

  GSTAGE(0);
#pragma unroll 4
  for (int kt = 0; kt < 32; ++kt) {
    if (kt < 31) {
      GSTAGE(kt + 1);
      asm volatile("s_waitcnt vmcnt(6)" ::: "memory");
    } else {
      asm volatile("s_waitcnt vmcnt(0)" ::: "memory");
    }
    __builtin_amdgcn_s_barrier();
    __builtin_amdgcn_sched_barrier(0);
    {
      const char* Sb_ = lds + (kt & 1) * 24576;
      bf16x8 ah[2], al[2], bh[4], bl[4];
#pragma unroll
      for (int ni = 0; ni < 4; ++ni) {
        bh[ni] = *(const bf16x8*)(Sb_ +  8192 + boffb + ni * 1024);
        bl[ni] = *(const bf16x8*)(Sb_ + 16384 + boffb + ni * 1024);
      }
#pragma unroll
      for (int mi = 0; mi < 2; ++mi) {
        ah[mi] = *(const bf16x8*)(Sb_ +        aoffb + mi * 1024);
        al[mi] = *(const bf16x8*)(Sb_ + 4096 + aoffb + mi * 1024);
      }
      __builtin_amdgcn_s_setprio(1);
#pragma unroll
      for (int mi = 0; mi < 2; ++mi)
#pragma unroll
        for (int ni = 0; ni < 4; ++ni) {
          acc[mi][ni] = __builtin_amdgcn_mfma_f32_16x16x32_bf16(ah[mi], bh[ni], acc[mi][ni], 0, 0, 0);
          acc[mi][ni] = __builtin_amdgcn_mfma_f32_16x16x32_bf16(ah[mi], bl[ni], acc[mi][ni], 0, 0, 0);
          acc[mi][ni] = __builtin_amdgcn_mfma_f32_16x16x32_bf16(al[mi], bh[ni], acc[mi][ni], 0, 0, 0);
        }
      __builtin_amdgcn_s_setprio(0);
    }
    __builtin_amdgcn_sched_barrier(0);
    __builtin_amdgcn_s_barrier();
  }

#pragma unroll
  for (int mi = 0; mi < 2; ++mi) {
#pragma unroll
    for (int r = 0; r < 4; ++r) {
      const int n = rowbase + wm*32 + mi*16 + l4*4 + r;
#pragma unroll
      for (int ni = 0; ni < 4; ++ni) {
        const int d = colbase + wn*64 + ni*16 + l15;
        const float v = acc[mi][ni][r];
        Gt[(size_t)n * DDIM + d] = v;
        Gtq[(size_t)n * DDIM + d] = f32_to_e4m3(v);
      }
    }
  }
}

// ====== 128x256 MX-FP8 scoring: 32x32x64 f8f6f4 MFMA, BK=64, dbuf =============
// R6 skeleton: 512 thr (8 waves, 2Mx4N), per-wave 64x64 out = acc[2][2] f32x16.
// LDS slot 24 KB {A [128 rows][64B fp8] at +0, B [256 rows][64B] at +8192},
// dbuf 48 KB -> 2 blocks/CU. STAGING RULE: gload_lds dest = base + t*16 (3
// calls/iter). Quad-swizzle as R6: content(phys p, row r) = logical p^s,
// s = (r>>1)&3; source slot sce = (t&3)^((t>>3)&3); reads recompute s from
// lane (row offsets 32/64/128 are all 0 mod 8). 64-lane bank audit: 8
// lanes/quad uniform -> conflict-free. Fragment: lane l -> row/col l&31,
// k-group (l>>5)*32; operand = 2 x b128 (logical chunks 2kg, 2kg+1; second
// addr = first ^ 16). A/B filled identically -> any internal k-permutation
// cancels. C/D: col = l&31, row = (reg&3) + 8*(reg>>2) + 4*(l>>5) (m74/m101).
#define QSTAGE(KT) { \
  const int rb_ = ((KT) & 1) * 24576; \
  const int co_ = (KT)*64 + sce*16; \
  GLL(gA + (size_t)sr0 * 512 + co_,           lds + rb_ +         t*16); \
  GLL(gB + (size_t)sr0 * 512 + co_,           lds + rb_ +  8192 + t*16); \
  GLL(gB + (size_t)(sr0 + 128) * 512 + co_,   lds + rb_ + 16384 + t*16); }

#define QITER(T, DOSTAGE, WAITSTR) do { \
  if (DOSTAGE) QSTAGE((T) + 1); \
  asm volatile("s_waitcnt " WAITSTR ::: "memory"); \
  __builtin_amdgcn_s_barrier(); \
  __builtin_amdgcn_sched_barrier(0); \
  { \
    const char* Sb_ = lds + ((T) & 1) * 24576; \
    i32x8 bq[2]; \
    _Pragma("unroll") for (int np_ = 0; np_ < 2; ++np_) { \
      const int ba_ = boffq + np_ * 2048; \
      i32x4 lo_ = *(const i32x4*)(Sb_ + ba_); \
      i32x4 hi_ = *(const i32x4*)(Sb_ + (ba_ ^ 16)); \
      bq[np_] = __builtin_shufflevector(lo_, hi_, 0, 1, 2, 3, 4, 5, 6, 7); \
    } \
    __builtin_amdgcn_s_setprio(1); \
    _Pragma("unroll") for (int mp_ = 0; mp_ < 2; ++mp_) { \
      const int aa_ = aoffq + mp_ * 2048; \
      i32x4 lo_ = *(const i32x4*)(Sb_ + aa_); \
      i32x4 hi_ = *(const i32x4*)(Sb_ + (aa_ ^ 16)); \
      i32x8 aq_ = __builtin_shufflevector(lo_, hi_, 0, 1, 2, 3, 4, 5, 6, 7); \
      _Pragma("unroll") for (int np_ = 0; np_ < 2; ++np_) \
        acc[mp_][np_] = __builtin_amdgcn_mfma_scale_f32_32x32x64_f8f6f4( \
            aq_, bq[np_], acc[mp_][np_], 0, 0, 0, 0x7F7F7F7F, 0, 0x7F7F7F7F); \
    } \
    __builtin_amdgcn_s_setprio(0); \
  } \
  __builtin_amdgcn_sched_barrier(0); \
  __builtin_amdgcn_s_barrier(); \
} while (0)

__global__ __launch_bounds__(512, 4) void k_score(
    const unsigned char* __restrict__ xq,    // [16384][512] fp8
    const unsigned char* __restrict__ Gtq,   // [8192][512]  fp8
    const float* __restrict__ csq,           // [8192]
    unsigned int* __restrict__ rowminG,      // [16384] key-encoded, init 0xFF
    unsigned int* __restrict__ cnt,          // [16384]
    int* __restrict__ candI)                 // [16384][CAND_MAX]
{
  __shared__ __align__(16) char lds[49152];
  __shared__ unsigned int rowthr[128];

  const int t = threadIdx.x;
  const int wave = t >> 6;
  const int lane = t & 63;
  const int l31 = lane & 31;
  const int kg  = lane >> 5;
  const int wm = wave >> 2;   // 2 waves in M (64 rows each)
  const int wn = wave & 3;    // 4 waves in N (64 cols each)

  const int bid = blockIdx.x;
  const int sbid = (bid & 7) * 512 + (bid >> 3);
  const int n_blk = sbid >> 7;   // 0..31
  const int m_blk = sbid & 127;  // 0..127
  const int rowbase = m_blk * 128;
  const int colbase = n_blk * 256;

  const unsigned char* gA = xq  + (size_t)rowbase * 512;
  const unsigned char* gB = Gtq + (size_t)colbase * 512;

  const int sr0 = t >> 2;                     // 0..127
  const int sce = (t & 3) ^ ((t >> 3) & 3);   // inverse-swizzled source slot

  if (t < 128) rowthr[t] = 0xFFFFFFFFu;

  // fragment read offsets: chunk part = phys chunk of logical 2kg
  const int cpart = ((2 * kg) ^ ((l31 >> 1) & 3)) * 16;
  const int aoffq = wm * 4096 + l31 * 64 + cpart;
  const int boffq = 8192 + wn * 4096 + l31 * 64 + cpart;

  f32x16 acc[2][2];
  const f32x16 zero16 = {0,0,0,0,0,0,0,0,0,0,0,0,0,0,0,0};
#pragma unroll
  for (int i = 0; i < 2; ++i)
#pragma unroll
    for (int j = 0; j < 2; ++j) acc[i][j] = zero16;

  QSTAGE(0);
  QITER(0, 1, "vmcnt(3)");
  QITER(1, 1, "vmcnt(3)");
  QITER(2, 1, "vmcnt(3)");
  QITER(3, 1, "vmcnt(3)");
  QITER(4, 1, "vmcnt(3)");
  QITER(5, 1, "vmcnt(3)");
  QITER(6, 1, "vmcnt(3)");
  QITER(7, 0, "vmcnt(0)");

  // ---- epilogue: s = csq - 2*dot ; block/global running min ; capture ----
  const int l5 = kg;
  float csqv[2];
#pragma unroll
  for (int np = 0; np < 2; ++np) csqv[np] = csq[colbase + wn*64 + np*32 + l31];

#pragma unroll
  for (int mp = 0; mp < 2; ++mp) {
#pragma unroll
    for (int reg = 0; reg < 16; ++reg) {
      float mn = fminf(fmaf(-2.0f, acc[mp][0][reg], csqv[0]),
                       fmaf(-2.0f, acc[mp][1][reg], csqv[1]));
#pragma unroll
      for (int msk = 1; msk < 32; msk <<= 1) mn = fminf(mn, __shfl_xor(mn, msk, 64));
      if (l31 == 0) {
        const int rowl = wm*64 + mp*32 + (reg & 3) + 8*(reg >> 2) + 4*l5;
        atomicMin(&rowthr[rowl], f2key(mn));
      }
    }
  }
  __syncthreads();
  if (t < 128) {
    unsigned int lk = rowthr[t];
    unsigned int old = atomicMin(&rowminG[rowbase + t], lk);
    if (old < lk) atomicMin(&rowthr[t], old);
  }
  __syncthreads();
#pragma unroll
  for (int mp = 0; mp < 2; ++mp) {
#pragma unroll
    for (int reg = 0; reg < 16; ++reg) {
      const int rowl = wm*64 + mp*32 + (reg & 3) + 8*(reg >> 2) + 4*l5;
      const float thr = key2f(rowthr[rowl]) + SCORE_DELTA;
#pragma unroll
      for (int np = 0; np < 2; ++np) {
        float sv = fmaf(-2.0f, acc[mp][np][reg], csqv[np]);
        if (sv <= thr) {
          const int grow = rowbase + rowl;
          unsigned int old = atomicAdd(&cnt[grow], 1u);
          if (old < CAND_MAX)
            candI[(size_t)grow * CAND_MAX + old] = colbase + wn*64 + np*32 + l31;
        }
      }
    }
  }
}

// ------- exact rescore: one candidate per lane, fp32 dot + fp64 combine ------
__global__ __launch_bounds__(256) void k_fixup(const float* __restrict__ x,
    const float* __restrict__ lnw, const float* __restrict__ lnb,
    const float* __restrict__ Gt, const double* __restrict__ csq_d,
    const unsigned int* __restrict__ cnt, const int* __restrict__ candI,
    int* __restrict__ out) {
  __shared__ float xs[4][DDIM];
  const int wave = threadIdx.x >> 6;
  const int lane = threadIdx.x & 63;
  const int row = blockIdx.x * 4 + wave;

  const float4* xr = (const float4*)(x + (size_t)row * DDIM);
  float4 v0 = xr[2*lane], v1 = xr[2*lane+1];
  float s = v0.x + v0.y + v0.z + v0.w + v1.x + v1.y + v1.z + v1.w;
#pragma unroll
  for (int m = 1; m < 64; m <<= 1) s += __shfl_xor(s, m, 64);
  const float mu = s * (1.0f / DDIM);
  float a0 = v0.x - mu, a1 = v0.y - mu, a2 = v0.z - mu, a3 = v0.w - mu;
  float a4 = v1.x - mu, a5 = v1.y - mu, a6 = v1.z - mu, a7 = v1.w - mu;
  float q = a0*a0 + a1*a1 + a2*a2 + a3*a3 + a4*a4 + a5*a5 + a6*a6 + a7*a7;
#pragma unroll
  for (int m = 1; m < 64; m <<= 1) q += __shfl_xor(q, m, 64);
  const float inv = rsqrtf(q * (1.0f / DDIM) + LN_EPS);
  const float4* wr = (const float4*)lnw;
  const float4* br = (const float4*)lnb;
  float4 w0 = wr[2*lane], w1 = wr[2*lane+1];
  float4 b0 = br[2*lane], b1 = br[2*lane+1];
  const float y0 = a0*inv*w0.x + b0.x, y1 = a1*inv*w0.y + b0.y;
  const float y2 = a2*inv*w0.z + b0.z, y3 = a3*inv*w0.w + b0.w;
  const float y4 = a4*inv*w1.x + b1.x, y5 = a5*inv*w1.y + b1.y;
  const float y6 = a6*inv*w1.z + b1.z, y7 = a7*inv*w1.w + b1.w;
  ((float4*)xs[wave])[2*lane]   = make_float4(y0, y1, y2, y3);
  ((float4*)xs[wave])[2*lane+1] = make_float4(y4, y5, y6, y7);

  const unsigned int count = cnt[row];
  double bs = 1e300;
  int bi = 0x7FFFFFFF;
  if (count <= CAND_MAX) {
    // parallel: lane i rescopes candidate i exactly (fp32 fmaf dot, fp64 tail)
    int n = (lane < (int)count) ? candI[(size_t)row * CAND_MAX + lane] : -1;
    if (n >= 0) {
      const float4* gr = (const float4*)(Gt + (size_t)n * DDIM);
      const float4* xv4 = (const float4*)xs[wave];
      float p = 0.f;
#pragma unroll 8
      for (int d4 = 0; d4 < DDIM / 4; ++d4) {
        float4 g = gr[d4];
        float4 xv = xv4[d4];
        p = fmaf(xv.x, g.x, p); p = fmaf(xv.y, g.y, p);
        p = fmaf(xv.z, g.z, p); p = fmaf(xv.w, g.w, p);
      }
      bs = csq_d[n] - 2.0 * (double)p;
      bi = n;
    }
#pragma unroll
    for (int m = 1; m < 64; m <<= 1) {
      double os = __shfl_xor(bs, m, 64);
      int oi = __shfl_xor(bi, m, 64);
      if (os < bs || (os == bs && oi < bi)) { bs = os; bi = oi; }
    }
    if (lane == 0) out[row] = bi;
  } else {
    // overflow: exact scan of all columns for this row (rare)
    for (int n = lane; n < CDIM; n += 64) {
      const float* g = Gt + (size_t)n * DDIM;
      float p = 0.f;
      for (int d = 0; d < DDIM; ++d) p = fmaf(xs[wave][d], g[d], p);
      double sc = csq_d[n] - 2.0 * (double)p;
      if (sc < bs || (sc == bs && n < bi)) { bs = sc; bi = n; }
    }
#pragma unroll
    for (int m = 1; m < 64; m <<= 1) {
      double os = __shfl_xor(bs, m, 64);
      int oi = __shfl_xor(bi, m, 64);
      if (os < bs || (os == bs && oi < bi)) { bs = os; bi = oi; }
    }
    if (lane == 0) out[row] = bi;
  }
}

extern "C" void kernel_launch(void* const* d_in, const int* in_sizes, int n_in,
                              void* d_out, int out_size, void* d_ws, size_t ws_size,
                              hipStream_t stream) {
  const float* x   = (const float*)d_in[0];
  const float* lnw = (const float*)d_in[1];
  const float* lnb = (const float*)d_in[2];
  const float* W   = (const float*)d_in[3];
  const float* cb  = (const float*)d_in[4];
  int* out = (int*)d_out;

  char* ws = (char*)d_ws;
  size_t off = 0;
  unsigned char*  xq  = (unsigned char*)(ws + off);  off += (size_t)MROWS * DDIM;         // 8MB
  float*          Gt  = (float*)(ws + off);          off += (size_t)CDIM * DDIM * 4;      // 16MB
  unsigned char*  Gtq = (unsigned char*)(ws + off);  off += (size_t)CDIM * DDIM;          // 4MB
  unsigned short* cbTh= (unsigned short*)(ws + off); off += (size_t)CDIM * HDIM * 2;      // 16MB
  unsigned short* cbTl= (unsigned short*)(ws + off); off += (size_t)CDIM * HDIM * 2;      // 16MB
  unsigned short* WTh = (unsigned short*)(ws + off); off += (size_t)DDIM * HDIM * 2;      // 1MB
  unsigned short* WTl = (unsigned short*)(ws + off); off += (size_t)DDIM * HDIM * 2;      // 1MB
  float*          csqf= (float*)(ws + off);          off += (size_t)CDIM * 4;
  double*         csqd= (double*)(ws + off);         off += (size_t)CDIM * 8;
  unsigned int*   cnt = (unsigned int*)(ws + off);   off += (size_t)MROWS * 4;
  unsigned int*   rmin= (unsigned int*)(ws + off);   off += (size_t)MROWS * 4;
  int*            candI=(int*)(ws + off);            off += (size_t)MROWS * CAND_MAX * 4; // 4MB

  k_lnq<<<MROWS / 4, 256, 0, stream>>>(x, lnw, lnb, xq, cnt, rmin);
  k_wsplit<<<DDIM / 64, 256, 0, stream>>>(W, WTh, WTl);
  k_cbsplit<<<CDIM / 64, 256, 0, stream>>>(cb, cbTh, cbTl, csqf, csqd);
  k_gproj2<<<(CDIM / 64) * (DDIM / 128), 256, 0, stream>>>(cbTh, cbTl, WTh, WTl, Gt, Gtq);
  k_score<<<(MROWS / 128) * (CDIM / 256), 512, 0, stream>>>(xq, Gtq, csqf, rmin, cnt, candI);
  k_fixup<<<MROWS / 4, 256, 0, stream>>>(x, lnw, lnb, Gt, csqd, cnt, candI, out);
}

// Round 12
// 698.488 us; speedup vs baseline: 3.7135x; 3.7135x over previous
//
#include <hip/hip_runtime.h>
#include <hip/hip_bf16.h>

#define MROWS 16384   // B*L
#define DDIM  512
#define HDIM  1024
#define CDIM  8192
#define LN_EPS 1e-5f
#define CAND_MAX 256
#define SCORE_DELTA 28.0f

typedef __attribute__((ext_vector_type(8))) short bf16x8;
typedef __attribute__((ext_vector_type(4))) float f32x4;
typedef __attribute__((ext_vector_type(16))) float f32x16;
typedef __attribute__((ext_vector_type(4))) int i32x4;
typedef __attribute__((ext_vector_type(8))) int i32x8;

__device__ __forceinline__ unsigned int f2key(float f) {
  unsigned int b = __float_as_uint(f);
  return (b & 0x80000000u) ? ~b : (b | 0x80000000u);
}
__device__ __forceinline__ float key2f(unsigned int k) {
  unsigned int b = (k & 0x80000000u) ? (k ^ 0x80000000u) : ~k;
  return __uint_as_float(b);
}

// Deterministic fp32 -> OCP e4m3fn (RNE, saturate to +-448). Software path:
// no intrinsic-API risk, and A/B sides use the identical mapping.
__device__ __forceinline__ unsigned char f32_to_e4m3(float f) {
  unsigned u = __float_as_uint(f);
  unsigned char sgn = (unsigned char)((u >> 24) & 0x80);
  unsigned ax = u & 0x7FFFFFFFu;
  float af = __uint_as_float(ax);
  if (af >= 448.f) return sgn | 0x7E;
  if (af < 0.015625f) {                 // subnormal: step 2^-9
    int m = (int)rintf(af * 512.f);
    if (m >= 8) return sgn | 0x08;
    return sgn | (unsigned char)m;
  }
  unsigned r = ax + 0x7FFFFu + ((ax >> 20) & 1u);   // RNE at mantissa bit 20
  int e = (int)(r >> 23) - 127 + 7;
  unsigned mant = (r >> 20) & 7u;
  if (e > 15 || (e == 15 && mant == 7)) return sgn | 0x7E;
  return sgn | (unsigned char)((e << 3) | mant);
}

// hi/lo bf16 split: x ~= hi + lo, captures ~17 mantissa bits.
__device__ __forceinline__ void bsplit(float v, unsigned short& h, unsigned short& l) {
  union { __hip_bfloat16 b; unsigned short u; } cv;
  cv.b = __float2bfloat16(v);
  h = cv.u;
  float fh = __bfloat162float(cv.b);
  cv.b = __float2bfloat16(v - fh);
  l = cv.u;
}

// -------- LayerNorm -> fp8 e4m3 (one wave per row, 4 rows/block) + init ------
__global__ __launch_bounds__(256) void k_lnq(const float* __restrict__ x,
                                             const float* __restrict__ lnw,
                                             const float* __restrict__ lnb,
                                             unsigned char* __restrict__ xq,
                                             unsigned int* __restrict__ cnt,
                                             unsigned int* __restrict__ rmin) {
  const int row = blockIdx.x * 4 + (threadIdx.x >> 6);
  const int t = threadIdx.x & 63;
  if (threadIdx.x < 4) {
    const int g = blockIdx.x * 4 + threadIdx.x;
    cnt[g] = 0u;
    rmin[g] = 0xFFFFFFFFu;
  }
  const float4* xr = (const float4*)(x + (size_t)row * DDIM);
  float4 v0 = xr[2 * t + 0];
  float4 v1 = xr[2 * t + 1];
  float s = v0.x + v0.y + v0.z + v0.w + v1.x + v1.y + v1.z + v1.w;
#pragma unroll
  for (int m = 1; m < 64; m <<= 1) s += __shfl_xor(s, m, 64);
  const float mu = s * (1.0f / DDIM);
  float a0 = v0.x - mu, a1 = v0.y - mu, a2 = v0.z - mu, a3 = v0.w - mu;
  float a4 = v1.x - mu, a5 = v1.y - mu, a6 = v1.z - mu, a7 = v1.w - mu;
  float q = a0*a0 + a1*a1 + a2*a2 + a3*a3 + a4*a4 + a5*a5 + a6*a6 + a7*a7;
#pragma unroll
  for (int m = 1; m < 64; m <<= 1) q += __shfl_xor(q, m, 64);
  const float inv = rsqrtf(q * (1.0f / DDIM) + LN_EPS);
  const float4* wr = (const float4*)lnw;
  const float4* br = (const float4*)lnb;
  float4 w0 = wr[2*t+0], w1 = wr[2*t+1];
  float4 b0 = br[2*t+0], b1 = br[2*t+1];
  float y[8];
  y[0] = a0*inv*w0.x + b0.x;  y[1] = a1*inv*w0.y + b0.y;
  y[2] = a2*inv*w0.z + b0.z;  y[3] = a3*inv*w0.w + b0.w;
  y[4] = a4*inv*w1.x + b1.x;  y[5] = a5*inv*w1.y + b1.y;
  y[6] = a6*inv*w1.z + b1.z;  y[7] = a7*inv*w1.w + b1.w;
  unsigned int w0b = 0, w1b = 0;
#pragma unroll
  for (int j = 0; j < 4; ++j) w0b |= (unsigned int)f32_to_e4m3(y[j]) << (8*j);
#pragma unroll
  for (int j = 0; j < 4; ++j) w1b |= (unsigned int)f32_to_e4m3(y[4+j]) << (8*j);
  *(uint2*)(xq + (size_t)row * DDIM + 8 * t) = make_uint2(w0b, w1b);
}

// ---- W[1024][512] -> WTh/WTl [512][1024] bf16 (transpose + hi/lo split) -----
__global__ __launch_bounds__(256) void k_wsplit(const float* __restrict__ W,
                                                unsigned short* __restrict__ WTh,
                                                unsigned short* __restrict__ WTl) {
  const int c = blockIdx.x * 64 + (threadIdx.x & 63);
  const int seg = threadIdx.x >> 6;
  for (int h0 = seg * 256; h0 < seg * 256 + 256; h0 += 8) {
    union { unsigned short u[8]; uint4 v; } oh, ol;
#pragma unroll
    for (int j = 0; j < 8; ++j) {
      float v = W[(size_t)(h0 + j) * DDIM + c];
      bsplit(v, oh.u[j], ol.u[j]);
    }
    *(uint4*)(WTh + (size_t)c * HDIM + h0) = oh.v;
    *(uint4*)(WTl + (size_t)c * HDIM + h0) = ol.v;
  }
}

// ---- cb[1024][8192] -> cbTh/cbTl [8192][1024] bf16 + csq (fp64, determ.) ----
__global__ __launch_bounds__(256) void k_cbsplit(const float* __restrict__ cb,
                                                 unsigned short* __restrict__ cbTh,
                                                 unsigned short* __restrict__ cbTl,
                                                 float* __restrict__ csq_f,
                                                 double* __restrict__ csq_d) {
  __shared__ double part[4][64];
  const int cl = threadIdx.x & 63;
  const int c = blockIdx.x * 64 + cl;
  const int seg = threadIdx.x >> 6;
  double sq = 0.0;
  for (int h0 = seg * 256; h0 < seg * 256 + 256; h0 += 8) {
    union { unsigned short u[8]; uint4 v; } oh, ol;
#pragma unroll
    for (int j = 0; j < 8; ++j) {
      float v = cb[(size_t)(h0 + j) * CDIM + c];
      sq += (double)v * (double)v;
      bsplit(v, oh.u[j], ol.u[j]);
    }
    *(uint4*)(cbTh + (size_t)c * HDIM + h0) = oh.v;
    *(uint4*)(cbTl + (size_t)c * HDIM + h0) = ol.v;
  }
  part[seg][cl] = sq;
  __syncthreads();
  if (threadIdx.x < 64) {
    double a = ((part[0][threadIdx.x] + part[1][threadIdx.x]) +
                part[2][threadIdx.x]) + part[3][threadIdx.x];
    csq_d[c] = a;
    csq_f[c] = (float)a;
  }
}

#define GLL(SRC, DST) __builtin_amdgcn_global_load_lds( \
    (const __attribute__((address_space(1))) unsigned int*)(SRC), \
    (__attribute__((address_space(3))) unsigned int*)(DST), 16, 0, 0)

// ==== Gt[n][d] via bf16x3 MFMA: 64n x 128d tile, K=1024, BK=32, dbuf =========
// (verified R10 engine, epilogue: Gt fp32 + Gtq fp8)
#define GSTAGE(KT) { \
  const int rb_ = ((KT) & 1) * 24576; \
  const int co_ = (KT)*32 + sce*8; \
  GLL(gAh + (size_t)sr0 * HDIM + co_,        lds + rb_ +          t*16); \
  GLL(gAl + (size_t)sr0 * HDIM + co_,        lds + rb_ +  4096 +  t*16); \
  GLL(gBh + (size_t)sr0 * HDIM + co_,        lds + rb_ +  8192 +  t*16); \
  GLL(gBh + (size_t)(sr0 + 64) * HDIM + co_, lds + rb_ + 12288 +  t*16); \
  GLL(gBl + (size_t)sr0 * HDIM + co_,        lds + rb_ + 16384 +  t*16); \
  GLL(gBl + (size_t)(sr0 + 64) * HDIM + co_, lds + rb_ + 20480 +  t*16); }

__global__ __launch_bounds__(256) void k_gproj2(
    const unsigned short* __restrict__ cbTh, const unsigned short* __restrict__ cbTl,
    const unsigned short* __restrict__ WTh,  const unsigned short* __restrict__ WTl,
    float* __restrict__ Gt, unsigned char* __restrict__ Gtq) {
  __shared__ __align__(16) char lds[49152];
  const int t = threadIdx.x;
  const int wave = t >> 6;
  const int lane = t & 63;
  const int l15 = lane & 15;
  const int l4  = lane >> 4;
  const int wm = wave >> 1;
  const int wn = wave & 1;

  const int bid = blockIdx.x;
  const int sbid = (bid & 7) * 64 + (bid >> 3);
  const int d_blk = sbid >> 7;
  const int m_blk = sbid & 127;
  const int rowbase = m_blk * 64;
  const int colbase = d_blk * 128;

  const unsigned short* gAh = cbTh + (size_t)rowbase * HDIM;
  const unsigned short* gAl = cbTl + (size_t)rowbase * HDIM;
  const unsigned short* gBh = WTh + (size_t)colbase * HDIM;
  const unsigned short* gBl = WTl + (size_t)colbase * HDIM;

  const int sr0 = t >> 2;
  const int sce = (t & 3) ^ ((t >> 3) & 3);

  const int swz = ((l4 ^ ((l15 >> 1) & 3)) << 4);
  const int aoffb = (wm * 32 + l15) * 64 + swz;
  const int boffb = (wn * 64 + l15) * 64 + swz;

  f32x4 acc[2][4];
#pragma unroll
  for (int i = 0; i < 2; ++i)
#pragma unroll
    for (int j = 0; j < 4; ++j) acc[i][j] = (f32x4){0.f, 0.f, 0.f, 0.f};

  GSTAGE(0);
#pragma unroll 4
  for (int kt = 0; kt < 32; ++kt) {
    if (kt < 31) {
      GSTAGE(kt + 1);
      asm volatile("s_waitcnt vmcnt(6)" ::: "memory");
    } else {
      asm volatile("s_waitcnt vmcnt(0)" ::: "memory");
    }
    __builtin_amdgcn_s_barrier();
    __builtin_amdgcn_sched_barrier(0);
    {
      const char* Sb_ = lds + (kt & 1) * 24576;
      bf16x8 ah[2], al[2], bh[4], bl[4];
#pragma unroll
      for (int ni = 0; ni < 4; ++ni) {
        bh[ni] = *(const bf16x8*)(Sb_ +  8192 + boffb + ni * 1024);
        bl[ni] = *(const bf16x8*)(Sb_ + 16384 + boffb + ni * 1024);
      }
#pragma unroll
      for (int mi = 0; mi < 2; ++mi) {
        ah[mi] = *(const bf16x8*)(Sb_ +        aoffb + mi * 1024);
        al[mi] = *(const bf16x8*)(Sb_ + 4096 + aoffb + mi * 1024);
      }
      __builtin_amdgcn_s_setprio(1);
#pragma unroll
      for (int mi = 0; mi < 2; ++mi)
#pragma unroll
        for (int ni = 0; ni < 4; ++ni) {
          acc[mi][ni] = __builtin_amdgcn_mfma_f32_16x16x32_bf16(ah[mi], bh[ni], acc[mi][ni], 0, 0, 0);
          acc[mi][ni] = __builtin_amdgcn_mfma_f32_16x16x32_bf16(ah[mi], bl[ni], acc[mi][ni], 0, 0, 0);
          acc[mi][ni] = __builtin_amdgcn_mfma_f32_16x16x32_bf16(al[mi], bh[ni], acc[mi][ni], 0, 0, 0);
        }
      __builtin_amdgcn_s_setprio(0);
    }
    __builtin_amdgcn_sched_barrier(0);
    __builtin_amdgcn_s_barrier();
  }

#pragma unroll
  for (int mi = 0; mi < 2; ++mi) {
#pragma unroll
    for (int r = 0; r < 4; ++r) {
      const int n = rowbase + wm*32 + mi*16 + l4*4 + r;
#pragma unroll
      for (int ni = 0; ni < 4; ++ni) {
        const int d = colbase + wn*64 + ni*16 + l15;
        const float v = acc[mi][ni][r];
        Gt[(size_t)n * DDIM + d] = v;
        Gtq[(size_t)n * DDIM + d] = f32_to_e4m3(v);
      }
    }
  }
}

// ====== 128x256 MX-FP8 scoring: 32x32x64 f8f6f4 MFMA, BK=64, dbuf =============
// (verified R11 engine, unchanged; only SCORE_DELTA/CAND_MAX constants differ)
#define QSTAGE(KT) { \
  const int rb_ = ((KT) & 1) * 24576; \
  const int co_ = (KT)*64 + sce*16; \
  GLL(gA + (size_t)sr0 * 512 + co_,           lds + rb_ +         t*16); \
  GLL(gB + (size_t)sr0 * 512 + co_,           lds + rb_ +  8192 + t*16); \
  GLL(gB + (size_t)(sr0 + 128) * 512 + co_,   lds + rb_ + 16384 + t*16); }

#define QITER(T, DOSTAGE, WAITSTR) do { \
  if (DOSTAGE) QSTAGE((T) + 1); \
  asm volatile("s_waitcnt " WAITSTR ::: "memory"); \
  __builtin_amdgcn_s_barrier(); \
  __builtin_amdgcn_sched_barrier(0); \
  { \
    const char* Sb_ = lds + ((T) & 1) * 24576; \
    i32x8 bq[2]; \
    _Pragma("unroll") for (int np_ = 0; np_ < 2; ++np_) { \
      const int ba_ = boffq + np_ * 2048; \
      i32x4 lo_ = *(const i32x4*)(Sb_ + ba_); \
      i32x4 hi_ = *(const i32x4*)(Sb_ + (ba_ ^ 16)); \
      bq[np_] = __builtin_shufflevector(lo_, hi_, 0, 1, 2, 3, 4, 5, 6, 7); \
    } \
    __builtin_amdgcn_s_setprio(1); \
    _Pragma("unroll") for (int mp_ = 0; mp_ < 2; ++mp_) { \
      const int aa_ = aoffq + mp_ * 2048; \
      i32x4 lo_ = *(const i32x4*)(Sb_ + aa_); \
      i32x4 hi_ = *(const i32x4*)(Sb_ + (aa_ ^ 16)); \
      i32x8 aq_ = __builtin_shufflevector(lo_, hi_, 0, 1, 2, 3, 4, 5, 6, 7); \
      _Pragma("unroll") for (int np_ = 0; np_ < 2; ++np_) \
        acc[mp_][np_] = __builtin_amdgcn_mfma_scale_f32_32x32x64_f8f6f4( \
            aq_, bq[np_], acc[mp_][np_], 0, 0, 0, 0x7F7F7F7F, 0, 0x7F7F7F7F); \
    } \
    __builtin_amdgcn_s_setprio(0); \
  } \
  __builtin_amdgcn_sched_barrier(0); \
  __builtin_amdgcn_s_barrier(); \
} while (0)

__global__ __launch_bounds__(512, 4) void k_score(
    const unsigned char* __restrict__ xq,    // [16384][512] fp8
    const unsigned char* __restrict__ Gtq,   // [8192][512]  fp8
    const float* __restrict__ csq,           // [8192]
    unsigned int* __restrict__ rowminG,      // [16384] key-encoded, init 0xFF
    unsigned int* __restrict__ cnt,          // [16384]
    int* __restrict__ candI)                 // [16384][CAND_MAX]
{
  __shared__ __align__(16) char lds[49152];
  __shared__ unsigned int rowthr[128];

  const int t = threadIdx.x;
  const int wave = t >> 6;
  const int lane = t & 63;
  const int l31 = lane & 31;
  const int kg  = lane >> 5;
  const int wm = wave >> 2;   // 2 waves in M (64 rows each)
  const int wn = wave & 3;    // 4 waves in N (64 cols each)

  const int bid = blockIdx.x;
  const int sbid = (bid & 7) * 512 + (bid >> 3);
  const int n_blk = sbid >> 7;   // 0..31
  const int m_blk = sbid & 127;  // 0..127
  const int rowbase = m_blk * 128;
  const int colbase = n_blk * 256;

  const unsigned char* gA = xq  + (size_t)rowbase * 512;
  const unsigned char* gB = Gtq + (size_t)colbase * 512;

  const int sr0 = t >> 2;                     // 0..127
  const int sce = (t & 3) ^ ((t >> 3) & 3);   // inverse-swizzled source slot

  if (t < 128) rowthr[t] = 0xFFFFFFFFu;

  // fragment read offsets: chunk part = phys chunk of logical 2kg
  const int cpart = ((2 * kg) ^ ((l31 >> 1) & 3)) * 16;
  const int aoffq = wm * 4096 + l31 * 64 + cpart;
  const int boffq = 8192 + wn * 4096 + l31 * 64 + cpart;

  f32x16 acc[2][2];
  const f32x16 zero16 = {0,0,0,0,0,0,0,0,0,0,0,0,0,0,0,0};
#pragma unroll
  for (int i = 0; i < 2; ++i)
#pragma unroll
    for (int j = 0; j < 2; ++j) acc[i][j] = zero16;

  QSTAGE(0);
  QITER(0, 1, "vmcnt(3)");
  QITER(1, 1, "vmcnt(3)");
  QITER(2, 1, "vmcnt(3)");
  QITER(3, 1, "vmcnt(3)");
  QITER(4, 1, "vmcnt(3)");
  QITER(5, 1, "vmcnt(3)");
  QITER(6, 1, "vmcnt(3)");
  QITER(7, 0, "vmcnt(0)");

  // ---- epilogue: s = csq - 2*dot ; block/global running min ; capture ----
  const int l5 = kg;
  float csqv[2];
#pragma unroll
  for (int np = 0; np < 2; ++np) csqv[np] = csq[colbase + wn*64 + np*32 + l31];

#pragma unroll
  for (int mp = 0; mp < 2; ++mp) {
#pragma unroll
    for (int reg = 0; reg < 16; ++reg) {
      float mn = fminf(fmaf(-2.0f, acc[mp][0][reg], csqv[0]),
                       fmaf(-2.0f, acc[mp][1][reg], csqv[1]));
#pragma unroll
      for (int msk = 1; msk < 32; msk <<= 1) mn = fminf(mn, __shfl_xor(mn, msk, 64));
      if (l31 == 0) {
        const int rowl = wm*64 + mp*32 + (reg & 3) + 8*(reg >> 2) + 4*l5;
        atomicMin(&rowthr[rowl], f2key(mn));
      }
    }
  }
  __syncthreads();
  if (t < 128) {
    unsigned int lk = rowthr[t];
    unsigned int old = atomicMin(&rowminG[rowbase + t], lk);
    if (old < lk) atomicMin(&rowthr[t], old);
  }
  __syncthreads();
#pragma unroll
  for (int mp = 0; mp < 2; ++mp) {
#pragma unroll
    for (int reg = 0; reg < 16; ++reg) {
      const int rowl = wm*64 + mp*32 + (reg & 3) + 8*(reg >> 2) + 4*l5;
      const float thr = key2f(rowthr[rowl]) + SCORE_DELTA;
#pragma unroll
      for (int np = 0; np < 2; ++np) {
        float sv = fmaf(-2.0f, acc[mp][np][reg], csqv[np]);
        if (sv <= thr) {
          const int grow = rowbase + rowl;
          unsigned int old = atomicAdd(&cnt[grow], 1u);
          if (old < CAND_MAX)
            candI[(size_t)grow * CAND_MAX + old] = colbase + wn*64 + np*32 + l31;
        }
      }
    }
  }
}

// ------- exact rescore: chunked candidates (64 lanes/chunk), fp32+fp64 -------
__global__ __launch_bounds__(256) void k_fixup(const float* __restrict__ x,
    const float* __restrict__ lnw, const float* __restrict__ lnb,
    const float* __restrict__ Gt, const double* __restrict__ csq_d,
    const unsigned int* __restrict__ cnt, const int* __restrict__ candI,
    int* __restrict__ out) {
  __shared__ float xs[4][DDIM];
  const int wave = threadIdx.x >> 6;
  const int lane = threadIdx.x & 63;
  const int row = blockIdx.x * 4 + wave;

  const float4* xr = (const float4*)(x + (size_t)row * DDIM);
  float4 v0 = xr[2*lane], v1 = xr[2*lane+1];
  float s = v0.x + v0.y + v0.z + v0.w + v1.x + v1.y + v1.z + v1.w;
#pragma unroll
  for (int m = 1; m < 64; m <<= 1) s += __shfl_xor(s, m, 64);
  const float mu = s * (1.0f / DDIM);
  float a0 = v0.x - mu, a1 = v0.y - mu, a2 = v0.z - mu, a3 = v0.w - mu;
  float a4 = v1.x - mu, a5 = v1.y - mu, a6 = v1.z - mu, a7 = v1.w - mu;
  float q = a0*a0 + a1*a1 + a2*a2 + a3*a3 + a4*a4 + a5*a5 + a6*a6 + a7*a7;
#pragma unroll
  for (int m = 1; m < 64; m <<= 1) q += __shfl_xor(q, m, 64);
  const float inv = rsqrtf(q * (1.0f / DDIM) + LN_EPS);
  const float4* wr = (const float4*)lnw;
  const float4* br = (const float4*)lnb;
  float4 w0 = wr[2*lane], w1 = wr[2*lane+1];
  float4 b0 = br[2*lane], b1 = br[2*lane+1];
  const float y0 = a0*inv*w0.x + b0.x, y1 = a1*inv*w0.y + b0.y;
  const float y2 = a2*inv*w0.z + b0.z, y3 = a3*inv*w0.w + b0.w;
  const float y4 = a4*inv*w1.x + b1.x, y5 = a5*inv*w1.y + b1.y;
  const float y6 = a6*inv*w1.z + b1.z, y7 = a7*inv*w1.w + b1.w;
  ((float4*)xs[wave])[2*lane]   = make_float4(y0, y1, y2, y3);
  ((float4*)xs[wave])[2*lane+1] = make_float4(y4, y5, y6, y7);

  const unsigned int count = cnt[row];
  double bs = 1e300;
  int bi = 0x7FFFFFFF;
  const float4* xv4 = (const float4*)xs[wave];

  if (count <= CAND_MAX) {
    const int nch = ((int)count + 63) >> 6;
    for (int ch = 0; ch < nch; ++ch) {
      const int idx = ch * 64 + lane;
      int n = (idx < (int)count) ? candI[(size_t)row * CAND_MAX + idx] : -1;
      if (n >= 0) {
        const float4* gr = (const float4*)(Gt + (size_t)n * DDIM);
        float p = 0.f;
#pragma unroll 8
        for (int d4 = 0; d4 < DDIM / 4; ++d4) {
          float4 g = gr[d4];
          float4 xv = xv4[d4];
          p = fmaf(xv.x, g.x, p); p = fmaf(xv.y, g.y, p);
          p = fmaf(xv.z, g.z, p); p = fmaf(xv.w, g.w, p);
        }
        double sc = csq_d[n] - 2.0 * (double)p;
        if (sc < bs || (sc == bs && n < bi)) { bs = sc; bi = n; }
      }
    }
  } else {
    // overflow (statistically never): exact scan of all columns, chunked
    for (int ch = 0; ch < CDIM / 64; ++ch) {
      const int n = ch * 64 + lane;
      const float4* gr = (const float4*)(Gt + (size_t)n * DDIM);
      float p = 0.f;
#pragma unroll 8
      for (int d4 = 0; d4 < DDIM / 4; ++d4) {
        float4 g = gr[d4];
        float4 xv = xv4[d4];
        p = fmaf(xv.x, g.x, p); p = fmaf(xv.y, g.y, p);
        p = fmaf(xv.z, g.z, p); p = fmaf(xv.w, g.w, p);
      }
      double sc = csq_d[n] - 2.0 * (double)p;
      if (sc < bs || (sc == bs && n < bi)) { bs = sc; bi = n; }
    }
  }
#pragma unroll
  for (int m = 1; m < 64; m <<= 1) {
    double os = __shfl_xor(bs, m, 64);
    int oi = __shfl_xor(bi, m, 64);
    if (os < bs || (os == bs && oi < bi)) { bs = os; bi = oi; }
  }
  if (lane == 0) out[row] = bi;
}

extern "C" void kernel_launch(void* const* d_in, const int* in_sizes, int n_in,
                              void* d_out, int out_size, void* d_ws, size_t ws_size,
                              hipStream_t stream) {
  const float* x   = (const float*)d_in[0];
  const float* lnw = (const float*)d_in[1];
  const float* lnb = (const float*)d_in[2];
  const float* W   = (const float*)d_in[3];
  const float* cb  = (const float*)d_in[4];
  int* out = (int*)d_out;

  char* ws = (char*)d_ws;
  size_t off = 0;
  unsigned char*  xq  = (unsigned char*)(ws + off);  off += (size_t)MROWS * DDIM;         // 8MB
  float*          Gt  = (float*)(ws + off);          off += (size_t)CDIM * DDIM * 4;      // 16MB
  unsigned char*  Gtq = (unsigned char*)(ws + off);  off += (size_t)CDIM * DDIM;          // 4MB
  unsigned short* cbTh= (unsigned short*)(ws + off); off += (size_t)CDIM * HDIM * 2;      // 16MB
  unsigned short* cbTl= (unsigned short*)(ws + off); off += (size_t)CDIM * HDIM * 2;      // 16MB
  unsigned short* WTh = (unsigned short*)(ws + off); off += (size_t)DDIM * HDIM * 2;      // 1MB
  unsigned short* WTl = (unsigned short*)(ws + off); off += (size_t)DDIM * HDIM * 2;      // 1MB
  float*          csqf= (float*)(ws + off);          off += (size_t)CDIM * 4;
  double*         csqd= (double*)(ws + off);         off += (size_t)CDIM * 8;
  unsigned int*   cnt = (unsigned int*)(ws + off);   off += (size_t)MROWS * 4;
  unsigned int*   rmin= (unsigned int*)(ws + off);   off += (size_t)MROWS * 4;
  int*            candI=(int*)(ws + off);            off += (size_t)MROWS * CAND_MAX * 4; // 16MB

  k_lnq<<<MROWS / 4, 256, 0, stream>>>(x, lnw, lnb, xq, cnt, rmin);
  k_wsplit<<<DDIM / 64, 256, 0, stream>>>(W, WTh, WTl);
  k_cbsplit<<<CDIM / 64, 256, 0, stream>>>(cb, cbTh, cbTl, csqf, csqd);
  k_gproj2<<<(CDIM / 64) * (DDIM / 128), 256, 0, stream>>>(cbTh, cbTl, WTh, WTl, Gt, Gtq);
  k_score<<<(MROWS / 128) * (CDIM / 256), 512, 0, stream>>>(xq, Gtq, csqf, rmin, cnt, candI);
  k_fixup<<<MROWS / 4, 256, 0, stream>>>(x, lnw, lnb, Gt, csqd, cnt, candI, out);
}